// Round 1
// baseline (699.270 us; speedup 1.0000x reference)
//
#include <hip/hip_runtime.h>
#include <hip/hip_bf16.h>
#include <stdint.h>

typedef __bf16 bf16x8 __attribute__((ext_vector_type(8)));
typedef float f32x4 __attribute__((ext_vector_type(4)));

// ---- helpers ------------------------------------------------------------

__device__ inline void gload_lds16(const void* g, void* lds) {
  // async global->LDS, 16B per lane. LDS dest must be wave-uniform base;
  // HW writes base + lane*16.
  __builtin_amdgcn_global_load_lds(
      (const __attribute__((address_space(1))) uint32_t*)(uintptr_t)g,
      (__attribute__((address_space(3))) uint32_t*)(uintptr_t)lds,
      16, 0, 0);
}

__device__ inline short f2bf(float f) {
  union { float f; uint32_t u; } x; x.f = f;
  uint32_t u = x.u;
  u += 0x7fffu + ((u >> 16) & 1u);   // RNE
  return (short)(u >> 16);
}

// ---- fp32 -> bf16 convert (vectorized) ----------------------------------

__global__ __launch_bounds__(256) void cvt_f32_bf16(
    const float* __restrict__ in, short* __restrict__ out, int n4) {
  int i = blockIdx.x * 256 + threadIdx.x;
  if (i < n4) {
    float4 v = reinterpret_cast<const float4*>(in)[i];
    short4 o;
    o.x = f2bf(v.x); o.y = f2bf(v.y); o.z = f2bf(v.z); o.w = f2bf(v.w);
    reinterpret_cast<short4*>(out)[i] = o;
  }
}

// ---- GEMM: C[M,N] = A[M,K] @ B[N,K]^T, bf16 in, fp32 acc ---------------
// 128x128 tile, BK=32, 4 waves (2x2), each wave a 64x64 subtile = 4x4
// mfma_f32_16x16x32_bf16 fragments. m97 structure: global_load_lds width-16
// staging, double-buffered LDS, 2 barriers per K-step.
// EPI=0: bias + relu^2 -> bf16 store (short*).  EPI=1: bias -> f32 store.

template <int EPI>
__global__ __launch_bounds__(256, 2) void gemm_bt(
    const short* __restrict__ A, const short* __restrict__ B,
    const float* __restrict__ bias, void* __restrict__ Cout,
    int M, int N, int K) {
  __shared__ __align__(16) short lds[2][2][128 * 32];

  const int tid  = threadIdx.x;
  const int wave = tid >> 6;
  const int lane = tid & 63;
  const int brow = blockIdx.y;   // M tile
  const int bcol = blockIdx.x;   // N tile
  const int wr = wave >> 1, wc = wave & 1;

  f32x4 acc[4][4];
#pragma unroll
  for (int m = 0; m < 4; ++m)
#pragma unroll
    for (int n = 0; n < 4; ++n)
      acc[m][n] = (f32x4){0.f, 0.f, 0.f, 0.f};

  const int nk = K >> 5;

  auto stage = [&](int buf, int kt) {
#pragma unroll
    for (int j = 0; j < 2; ++j) {
      const int i = j * 256 + tid;           // flat 16B-chunk index, 0..511
      const int row = i >> 2, kc = (i & 3) * 8;
      const short* ga = A + (size_t)(brow * 128 + row) * K + kt * 32 + kc;
      gload_lds16(ga, (void*)&lds[buf][0][(j * 256 + wave * 64) * 8]);
      const short* gb = B + (size_t)(bcol * 128 + row) * K + kt * 32 + kc;
      gload_lds16(gb, (void*)&lds[buf][1][(j * 256 + wave * 64) * 8]);
    }
  };

  const int fr = lane & 15, kq = lane >> 4;   // fragment row / k-quarter

  auto compute = [&](int buf) {
    const short* ldsA = lds[buf][0];
    const short* ldsB = lds[buf][1];
    bf16x8 a[4], b[4];
#pragma unroll
    for (int m = 0; m < 4; ++m)
      a[m] = *(const bf16x8*)&ldsA[(wr * 64 + m * 16 + fr) * 32 + kq * 8];
#pragma unroll
    for (int n = 0; n < 4; ++n)
      b[n] = *(const bf16x8*)&ldsB[(wc * 64 + n * 16 + fr) * 32 + kq * 8];
#pragma unroll
    for (int m = 0; m < 4; ++m)
#pragma unroll
      for (int n = 0; n < 4; ++n)
        acc[m][n] = __builtin_amdgcn_mfma_f32_16x16x32_bf16(
            a[m], b[n], acc[m][n], 0, 0, 0);
  };

  stage(0, 0);
  __syncthreads();
  int cur = 0;
  for (int kt = 0; kt < nk - 1; ++kt) {
    stage(cur ^ 1, kt + 1);
    compute(cur);
    __syncthreads();
    cur ^= 1;
  }
  compute(cur);

  // epilogue: C/D layout col=lane&15, row=(lane>>4)*4+reg  [m89-verified]
  const int q = lane >> 4;
  if (EPI == 0) {
    short* C = (short*)Cout;
#pragma unroll
    for (int m = 0; m < 4; ++m) {
      const int row0 = brow * 128 + wr * 64 + m * 16 + q * 4;
#pragma unroll
      for (int n = 0; n < 4; ++n) {
        const int col = bcol * 128 + wc * 64 + n * 16 + fr;
        const float bv = bias[col];
#pragma unroll
        for (int j = 0; j < 4; ++j) {
          float v = acc[m][n][j] + bv;
          v = v > 0.f ? v * v : 0.f;   // squared ReLU
          C[(size_t)(row0 + j) * N + col] = f2bf(v);
        }
      }
    }
  } else {
    float* C = (float*)Cout;
#pragma unroll
    for (int m = 0; m < 4; ++m) {
      const int row0 = brow * 128 + wr * 64 + m * 16 + q * 4;
#pragma unroll
      for (int n = 0; n < 4; ++n) {
        const int col = bcol * 128 + wc * 64 + n * 16 + fr;
        const float bv = bias[col];
#pragma unroll
        for (int j = 0; j < 4; ++j)
          C[(size_t)(row0 + j) * N + col] = acc[m][n][j] + bv;
      }
    }
  }
}

// ---- launch -------------------------------------------------------------

extern "C" void kernel_launch(void* const* d_in, const int* in_sizes, int n_in,
                              void* d_out, int out_size, void* d_ws,
                              size_t ws_size, hipStream_t stream) {
  const float* x  = (const float*)d_in[0];
  const float* w1 = (const float*)d_in[1];
  const float* b1 = (const float*)d_in[2];
  const float* w2 = (const float*)d_in[3];
  const float* b2 = (const float*)d_in[4];
  float* out = (float*)d_out;

  const int H = in_sizes[2];            // 8192
  const int D = in_sizes[4];            // 2048
  const int M = in_sizes[0] / D;        // B*S = 8192

  // workspace layout (all bf16 as short):
  short* xb  = (short*)d_ws;                 // M*D
  short* w1b = xb  + (size_t)M * D;          // H*D
  short* w2b = w1b + (size_t)H * D;          // D*H
  short* act = w2b + (size_t)D * H;          // M*H

  {
    int n4 = (M * D) / 4;
    cvt_f32_bf16<<<(n4 + 255) / 256, 256, 0, stream>>>(x, xb, n4);
    n4 = (H * D) / 4;
    cvt_f32_bf16<<<(n4 + 255) / 256, 256, 0, stream>>>(w1, w1b, n4);
    n4 = (D * H) / 4;
    cvt_f32_bf16<<<(n4 + 255) / 256, 256, 0, stream>>>(w2, w2b, n4);
  }

  // GEMM1: [M,D] @ [H,D]^T -> sqrelu -> act[M,H] (bf16)
  gemm_bt<0><<<dim3(H / 128, M / 128), 256, 0, stream>>>(
      xb, w1b, b1, (void*)act, M, H, D);
  // GEMM2: [M,H] @ [D,H]^T -> + b2 -> out[M,D] (f32)
  gemm_bt<1><<<dim3(D / 128, M / 128), 256, 0, stream>>>(
      act, w2b, b2, (void*)out, M, D, H);
}

// Round 2
// 635.865 us; speedup vs baseline: 1.0997x; 1.0997x over previous
//
#include <hip/hip_runtime.h>
#include <hip/hip_bf16.h>
#include <stdint.h>

typedef __bf16 bf16x8 __attribute__((ext_vector_type(8)));
typedef float f32x4 __attribute__((ext_vector_type(4)));

// ---- helpers ------------------------------------------------------------

__device__ inline void gload_lds16(const void* g, void* lds) {
  // async global->LDS, 16B per lane. LDS dest is wave-uniform base;
  // HW writes base + lane*16. Global src is per-lane.
  __builtin_amdgcn_global_load_lds(
      (const __attribute__((address_space(1))) uint32_t*)(uintptr_t)g,
      (__attribute__((address_space(3))) uint32_t*)(uintptr_t)lds,
      16, 0, 0);
}

__device__ inline short f2bf(float f) {
  union { float f; uint32_t u; } x; x.f = f;
  uint32_t u = x.u;
  u += 0x7fffu + ((u >> 16) & 1u);   // RNE
  return (short)(u >> 16);
}

// ---- fp32 -> bf16 convert (vectorized) ----------------------------------

__global__ __launch_bounds__(256) void cvt_f32_bf16(
    const float* __restrict__ in, short* __restrict__ out, int n4) {
  int i = blockIdx.x * 256 + threadIdx.x;
  if (i < n4) {
    float4 v = reinterpret_cast<const float4*>(in)[i];
    short4 o;
    o.x = f2bf(v.x); o.y = f2bf(v.y); o.z = f2bf(v.z); o.w = f2bf(v.w);
    reinterpret_cast<short4*>(out)[i] = o;
  }
}

// ---- GEMM: C[M,N] = A[M,K] @ B[N,K]^T, bf16 in, fp32 acc ---------------
// 256x256 tile, BK=32, 8 waves (2Mx4N), per-wave 128x64 = acc[8][4] of
// mfma_f32_16x16x32_bf16. 4-slot LDS ring (depth-4 pipeline), counted
// vmcnt(8) at tile boundary (never drains to 0 in steady state), raw
// s_barrier, granule XOR-swizzle (T2), setprio around MFMA clusters (T5),
// bijective XCD-aware block swizzle (T1).
// Ring safety: stage T_{c+3} -> slot (c+3)&3 is issued after the barrier
// that ended compute of T_{c-1} (that slot's last reader), and T_c's data
// completeness is guaranteed by each wave's vmcnt(8) + barrier at the end
// of T_{c-1} (own loads for T_c are older than the 8 newest).
// EPI=0: bias + relu^2 -> bf16 store.  EPI=1: bias -> f32 store.

template <int EPI>
__global__ __launch_bounds__(512, 2) void gemm_bt(
    const short* __restrict__ A, const short* __restrict__ B,
    const float* __restrict__ bias, void* __restrict__ Cout,
    int M, int N, int K) {
  // [slot][A/B][256 rows * 32 k] bf16 = 4 * 32 KiB = 128 KiB
  __shared__ __align__(16) short lds[4][2][256 * 32];

  const int tid  = threadIdx.x;
  const int wave = tid >> 6;
  const int lane = tid & 63;
  const int wr = wave >> 2;          // 0..1 -> M half
  const int wc = wave & 3;           // 0..3 -> N quarter

  // T1: bijective XCD swizzle (nwg % 8 == 0 here), column-major in-chunk
  const int nwg = gridDim.x;
  const int w = (blockIdx.x & 7) * (nwg >> 3) + (blockIdx.x >> 3);
  const int gy = M >> 8;
  const int brow = w % gy;
  const int bcol = w / gy;

  f32x4 acc[8][4];
#pragma unroll
  for (int m = 0; m < 8; ++m)
#pragma unroll
    for (int n = 0; n < 4; ++n)
      acc[m][n] = (f32x4){0.f, 0.f, 0.f, 0.f};

  const int nk = K >> 5;             // K-tiles of 32

  const int fr = lane & 15, kq = lane >> 4;

  // ---- T2 swizzle: logical granule g=(row*4+kq) stored at physical
  // P = g ^ ((g>>3)&7). Involution (high bits preserved), residual 2-way
  // bank aliasing = free.
  // Read offsets (in shorts), loop-invariant per lane:
  int offA[8], offB[4];
#pragma unroll
  for (int m = 0; m < 8; ++m) {
    int row = wr * 128 + m * 16 + fr;
    int g = row * 4 + kq;
    offA[m] = (g ^ ((g >> 3) & 7)) * 8;
  }
#pragma unroll
  for (int n = 0; n < 4; ++n) {
    int row = wc * 64 + n * 16 + fr;
    int g = row * 4 + kq;
    offB[n] = (g ^ ((g >> 3) & 7)) * 8;
  }

  // ---- stage pointers: physical chunk i holds logical gl = i^((i>>3)&7).
  // Per-thread global pointers, advanced by 32 elems per staged tile.
  const int iA0 = tid, iA1 = 512 + tid;
  const int glA0 = iA0 ^ ((iA0 >> 3) & 7), glA1 = iA1 ^ ((iA1 >> 3) & 7);
  const short* pA0 = A + (size_t)(brow * 256 + (glA0 >> 2)) * K + (glA0 & 3) * 8;
  const short* pA1 = A + (size_t)(brow * 256 + (glA1 >> 2)) * K + (glA1 & 3) * 8;
  const short* pB0 = B + (size_t)(bcol * 256 + (glA0 >> 2)) * K + (glA0 & 3) * 8;
  const short* pB1 = B + (size_t)(bcol * 256 + (glA1 >> 2)) * K + (glA1 & 3) * 8;

  auto stageA = [&](int slot) {
    short* base = &lds[slot][0][0];
    gload_lds16(pA0, base + (wave * 64) * 8);
    gload_lds16(pA1, base + (512 + wave * 64) * 8);
    pA0 += 32; pA1 += 32;
  };
  auto stageB = [&](int slot) {
    short* base = &lds[slot][1][0];
    gload_lds16(pB0, base + (wave * 64) * 8);
    gload_lds16(pB1, base + (512 + wave * 64) * 8);
    pB0 += 32; pB1 += 32;
  };

  // ---- prologue: stage T0,T1,T2 (12 loads/thread); wait oldest 4 (=T0).
  stageA(0); stageB(0);
  stageA(1); stageB(1);
  stageA(2); stageB(2);
  asm volatile("s_waitcnt vmcnt(8)" ::: "memory");
  __builtin_amdgcn_s_barrier();
  asm volatile("" ::: "memory");

  for (int c = 0; c < nk; ++c) {
    const int slot = c & 3;
    const int sl3 = (c + 3) & 3;
    const bool do_stage = (c + 3) < nk;
    const short* sA = &lds[slot][0][0];
    const short* sB = &lds[slot][1][0];

    // phase A: stage A-half of T_{c+3}; read a[0..7], b0,b1; 16 MFMA
    if (do_stage) stageA(sl3);
    bf16x8 a[8];
#pragma unroll
    for (int m = 0; m < 8; ++m)
      a[m] = *(const bf16x8*)(sA + offA[m]);
    bf16x8 b0 = *(const bf16x8*)(sB + offB[0]);
    bf16x8 b1 = *(const bf16x8*)(sB + offB[1]);
    __builtin_amdgcn_s_setprio(1);
#pragma unroll
    for (int m = 0; m < 8; ++m) {
      acc[m][0] = __builtin_amdgcn_mfma_f32_16x16x32_bf16(a[m], b0, acc[m][0], 0, 0, 0);
      acc[m][1] = __builtin_amdgcn_mfma_f32_16x16x32_bf16(a[m], b1, acc[m][1], 0, 0, 0);
    }
    __builtin_amdgcn_s_setprio(0);

    // phase B: stage B-half of T_{c+3}; read b2,b3 (reuse a[]); 16 MFMA
    if (do_stage) stageB(sl3);
    bf16x8 b2 = *(const bf16x8*)(sB + offB[2]);
    bf16x8 b3 = *(const bf16x8*)(sB + offB[3]);
    __builtin_amdgcn_s_setprio(1);
#pragma unroll
    for (int m = 0; m < 8; ++m) {
      acc[m][2] = __builtin_amdgcn_mfma_f32_16x16x32_bf16(a[m], b2, acc[m][2], 0, 0, 0);
      acc[m][3] = __builtin_amdgcn_mfma_f32_16x16x32_bf16(a[m], b3, acc[m][3], 0, 0, 0);
    }
    __builtin_amdgcn_s_setprio(0);

    // tile boundary: counted wait (T_{c+2},T_{c+3} stay in flight) + barrier
    if (c < nk - 1) {
      const int rem = nk - 2 - c;   // staged tiles beyond T_{c+1}
      if (rem >= 2)      asm volatile("s_waitcnt vmcnt(8)" ::: "memory");
      else if (rem == 1) asm volatile("s_waitcnt vmcnt(4)" ::: "memory");
      else               asm volatile("s_waitcnt vmcnt(0)" ::: "memory");
      __builtin_amdgcn_s_barrier();
      asm volatile("" ::: "memory");
    }
  }

  // ---- epilogue: C/D layout col=lane&15, row=(lane>>4)*4+reg
  const int q = lane >> 4;
  if (EPI == 0) {
    short* C = (short*)Cout;
#pragma unroll
    for (int m = 0; m < 8; ++m) {
      const int row0 = brow * 256 + wr * 128 + m * 16 + q * 4;
#pragma unroll
      for (int n = 0; n < 4; ++n) {
        const int col = bcol * 256 + wc * 64 + n * 16 + fr;
        const float bv = bias[col];
#pragma unroll
        for (int j = 0; j < 4; ++j) {
          float v = acc[m][n][j] + bv;
          v = v > 0.f ? v * v : 0.f;   // squared ReLU
          C[(size_t)(row0 + j) * N + col] = f2bf(v);
        }
      }
    }
  } else {
    float* C = (float*)Cout;
#pragma unroll
    for (int m = 0; m < 8; ++m) {
      const int row0 = brow * 256 + wr * 128 + m * 16 + q * 4;
#pragma unroll
      for (int n = 0; n < 4; ++n) {
        const int col = bcol * 256 + wc * 64 + n * 16 + fr;
        const float bv = bias[col];
#pragma unroll
        for (int j = 0; j < 4; ++j)
          C[(size_t)(row0 + j) * N + col] = acc[m][n][j] + bv;
      }
    }
  }
}

// ---- launch -------------------------------------------------------------

extern "C" void kernel_launch(void* const* d_in, const int* in_sizes, int n_in,
                              void* d_out, int out_size, void* d_ws,
                              size_t ws_size, hipStream_t stream) {
  const float* x  = (const float*)d_in[0];
  const float* w1 = (const float*)d_in[1];
  const float* b1 = (const float*)d_in[2];
  const float* w2 = (const float*)d_in[3];
  const float* b2 = (const float*)d_in[4];
  float* out = (float*)d_out;

  const int H = in_sizes[2];            // 8192
  const int D = in_sizes[4];            // 2048
  const int M = in_sizes[0] / D;        // B*S = 8192

  // workspace layout (all bf16 as short):
  short* xb  = (short*)d_ws;                 // M*D
  short* w1b = xb  + (size_t)M * D;          // H*D
  short* w2b = w1b + (size_t)H * D;          // D*H
  short* act = w2b + (size_t)D * H;          // M*H

  {
    int n4 = (M * D) / 4;
    cvt_f32_bf16<<<(n4 + 255) / 256, 256, 0, stream>>>(x, xb, n4);
    n4 = (H * D) / 4;
    cvt_f32_bf16<<<(n4 + 255) / 256, 256, 0, stream>>>(w1, w1b, n4);
    n4 = (D * H) / 4;
    cvt_f32_bf16<<<(n4 + 255) / 256, 256, 0, stream>>>(w2, w2b, n4);
  }

  // GEMM1: [M,D] @ [H,D]^T -> sqrelu -> act[M,H] (bf16)
  gemm_bt<0><<<(M / 256) * (H / 256), 512, 0, stream>>>(
      xb, w1b, b1, (void*)act, M, H, D);
  // GEMM2: [M,H] @ [D,H]^T -> + b2 -> out[M,D] (f32)
  gemm_bt<1><<<(M / 256) * (D / 256), 512, 0, stream>>>(
      act, w2b, b2, (void*)out, M, D, H);
}

// Round 3
// 548.761 us; speedup vs baseline: 1.2743x; 1.1587x over previous
//
#include <hip/hip_runtime.h>
#include <hip/hip_bf16.h>
#include <stdint.h>

typedef __bf16 bf16x8 __attribute__((ext_vector_type(8)));
typedef float f32x4 __attribute__((ext_vector_type(4)));

// ---- helpers ------------------------------------------------------------

__device__ inline void gload_lds16(const void* g, void* lds) {
  // async global->LDS, 16B per lane. LDS dest is wave-uniform base;
  // HW writes base + lane*16. Global src is per-lane.
  __builtin_amdgcn_global_load_lds(
      (const __attribute__((address_space(1))) uint32_t*)(uintptr_t)g,
      (__attribute__((address_space(3))) uint32_t*)(uintptr_t)lds,
      16, 0, 0);
}

__device__ inline short f2bf(float f) {
  union { float f; uint32_t u; } x; x.f = f;
  uint32_t u = x.u;
  u += 0x7fffu + ((u >> 16) & 1u);   // RNE
  return (short)(u >> 16);
}

#define BAR() do { asm volatile("" ::: "memory"); \
                   __builtin_amdgcn_s_barrier();  \
                   asm volatile("" ::: "memory"); } while (0)

// ---- fp32 -> bf16 convert (vectorized) ----------------------------------

__global__ __launch_bounds__(256) void cvt_f32_bf16(
    const float* __restrict__ in, short* __restrict__ out, int n4) {
  int i = blockIdx.x * 256 + threadIdx.x;
  if (i < n4) {
    float4 v = reinterpret_cast<const float4*>(in)[i];
    short4 o;
    o.x = f2bf(v.x); o.y = f2bf(v.y); o.z = f2bf(v.z); o.w = f2bf(v.w);
    reinterpret_cast<short4*>(out)[i] = o;
  }
}

// ---- GEMM: C[M,N] = A[M,K] @ B[N,K]^T, bf16 in, fp32 acc ---------------
// m201-style 8-phase template: 256x256 tile, BK=64, 8 waves (2Mx4N),
// per-wave 128x64 = acc[8][4] of mfma_f32_16x16x32_bf16.
//
// LDS: 2 buffers x 4 half-tile slots x [128 rows x 64 k] bf16 = 128 KiB.
//   slot 0 (A0): A tile rows with bit6==0  ({0..63} u {128..191})
//   slot 1 (A1): A tile rows with bit6==1  ({64..127} u {192..255})
//   slot 2 (B0): B tile rows with bit5==0  (n-frags 0,1 of every wc)
//   slot 3 (B1): B tile rows with bit5==1  (n-frags 2,3 of every wc)
// Sliced so each slot is ds_read in EXACTLY one phase per tile:
//   Ph1 reads A0+B0, Ph2 reads B1, Ph3 reads A1, Ph4 reads nothing.
//
// Per K-tile t (cur=t&1, nxt=cur^1), phases (template: {reads ∥ 1 stage} →
// barrier → setprio1 16xMFMA setprio0 → barrier):
//   Ph1: stage A1(t+1)->nxt | read aq<-A0(cur), b0q<-B0(cur) | MFMA m0-3 x n0-1
//   Ph2: stage A0(t+2)->cur | read b1q<-B1(cur)              | MFMA m0-3 x n2-3
//   Ph3: stage B0(t+2)->cur | read aq<-A1(cur)               | MFMA m4-7 x n2-3
//   Ph4: stage B1(t+2)->cur |                                | MFMA m4-7 x n0-1
//   tile boundary: vmcnt(6) (the 3 newest half-tiles {A0,B0,B1}(t+2) stay
//   in flight) + barrier. NEVER vmcnt(0) except at t==nk-2 tail.
// Clobber ledger (stage vs last ds_read of same slot, >=2 barriers apart):
//   A1(t+1)->nxt: nxt.A1 last read Ph3(t-1). A0(t+2)->cur: read Ph1(t).
//   B0(t+2)->cur: read Ph1(t). B1(t+2)->cur: read Ph2(t).  All safe.
// Readiness ledger: issue order ...A0(x)@Ph2, B0(x)@Ph3, B1(x)@Ph4, A1(x)
// @Ph1-next; at boundary W(t), vmcnt(6) completes A1(t+1) and older =
// everything tile t+1 reads.  EPI=0: bias+relu^2->bf16; EPI=1: bias->f32.

template <int EPI>
__global__ __launch_bounds__(512, 2) void gemm_bt(
    const short* __restrict__ A, const short* __restrict__ B,
    const float* __restrict__ bias, void* __restrict__ Cout,
    int M, int N, int K) {
  __shared__ __align__(16) short lds[2][4][128 * 64];

  const int tid  = threadIdx.x;
  const int wave = tid >> 6;
  const int lane = tid & 63;
  const int wr = wave >> 2;          // 0..1 -> M half (128 rows)
  const int wc = wave & 3;           // 0..3 -> N quarter (64 cols)
  const int fr = lane & 15, kq = lane >> 4;

  // T1: bijective XCD swizzle (nwg % 8 == 0), column-major in-chunk
  const int nwg = gridDim.x;
  const int w = (blockIdx.x & 7) * (nwg >> 3) + (blockIdx.x >> 3);
  const int gy = M >> 8;
  const int brow = w % gy;
  const int bcol = w / gy;

  f32x4 acc[8][4];
#pragma unroll
  for (int m = 0; m < 8; ++m)
#pragma unroll
    for (int n = 0; n < 4; ++n)
      acc[m][n] = (f32x4){0.f, 0.f, 0.f, 0.f};

  const int nk = K >> 6;             // K-tiles of 64

  // ---- T2 swizzle (within a 128x64 slot): granule g = r*8 + gc (16B
  // granules, 8/row), stored at P = g ^ (r&7). Involution; ds_read_b128
  // lanes fr=0..15 then hit 8 distinct 4-bank groups (2-way = free).
  // Read byte-offsets, shared by slot pairs (A0/A1 and B0/B1):
  int offA[4][2], offB[2][2];
#pragma unroll
  for (int m = 0; m < 4; ++m)
#pragma unroll
    for (int kk = 0; kk < 2; ++kk) {
      int r = wr * 64 + m * 16 + fr;
      int g = r * 8 + kk * 4 + kq;
      offA[m][kk] = (g ^ (r & 7)) * 16;
    }
#pragma unroll
  for (int n = 0; n < 2; ++n)
#pragma unroll
    for (int kk = 0; kk < 2; ++kk) {
      int r = wc * 32 + n * 16 + fr;
      int g = r * 8 + kk * 4 + kq;
      offB[n][kk] = (g ^ (r & 7)) * 16;
    }

  // ---- stage source: physical granule i in {tid, 512+tid} holds logical
  // gl = i ^ ((i>>3)&7); slot row r = gl>>3, col granule c = gl&7.
  // Load1 row = load0 row + 64 in-slot = +128 in tile rows (both A and B).
  const int i0 = tid;
  const int gl0 = i0 ^ ((i0 >> 3) & 7);
  const int r0 = gl0 >> 3, c0 = gl0 & 7;
  const size_t rstep = (size_t)128 * K;

  const short* pA[2];
  const short* pB[2];
  {
    const int rb0 = (r0 >> 5) * 64 + (r0 & 31);
#pragma unroll
    for (int h = 0; h < 2; ++h) {
      pA[h] = A + (size_t)(brow * 256 + h * 64 + r0) * K + c0 * 8;
      pB[h] = B + (size_t)(bcol * 256 + rb0 + h * 32) * K + c0 * 8;
    }
  }

  const int dst0 = wave * 512, dst1 = 4096 + wave * 512;  // shorts in slot

#define STAGE(p, buf, slot)                              \
  do {                                                   \
    short* base_ = &lds[buf][slot][0];                   \
    gload_lds16((p), base_ + dst0);                      \
    gload_lds16((p) + rstep, base_ + dst1);              \
    (p) += 64;                                           \
  } while (0)

  // ---- prologue: steady-state issue order up to Ph1(0).
  STAGE(pA[0], 0, 0);   // A0(0)
  STAGE(pB[0], 0, 2);   // B0(0)
  STAGE(pB[1], 0, 3);   // B1(0)
  STAGE(pA[1], 0, 1);   // A1(0)
  STAGE(pA[0], 1, 0);   // A0(1)
  STAGE(pB[0], 1, 2);   // B0(1)
  STAGE(pB[1], 1, 3);   // B1(1)
  asm volatile("s_waitcnt vmcnt(6)" ::: "memory");  // tile 0 complete
  BAR();

  bf16x8 aq[4][2], b0q[2][2], b1q[2][2];

  for (int t = 0; t < nk; ++t) {
    const int cur = t & 1, nxt = cur ^ 1;
    const bool s1 = (t + 1) < nk, s2 = (t + 2) < nk;

    // ---------- Phase 1: stage A1(t+1) | read aq(A0), b0q(B0) | m0-3 x n0-1
    if (s1) STAGE(pA[1], nxt, 1);
    {
      const char* sA = (const char*)&lds[cur][0][0];
      const char* sB = (const char*)&lds[cur][2][0];
#pragma unroll
      for (int m = 0; m < 4; ++m)
#pragma unroll
        for (int kk = 0; kk < 2; ++kk)
          aq[m][kk] = *(const bf16x8*)(sA + offA[m][kk]);
#pragma unroll
      for (int n = 0; n < 2; ++n)
#pragma unroll
        for (int kk = 0; kk < 2; ++kk)
          b0q[n][kk] = *(const bf16x8*)(sB + offB[n][kk]);
    }
    BAR();
    __builtin_amdgcn_s_setprio(1);
#pragma unroll
    for (int m = 0; m < 4; ++m)
#pragma unroll
      for (int n = 0; n < 2; ++n)
#pragma unroll
        for (int kk = 0; kk < 2; ++kk)
          acc[m][n] = __builtin_amdgcn_mfma_f32_16x16x32_bf16(
              aq[m][kk], b0q[n][kk], acc[m][n], 0, 0, 0);
    __builtin_amdgcn_s_setprio(0);
    BAR();

    // ---------- Phase 2: stage A0(t+2) | read b1q(B1) | m0-3 x n2-3
    if (s2) STAGE(pA[0], cur, 0);
    {
      const char* sB = (const char*)&lds[cur][3][0];
#pragma unroll
      for (int n = 0; n < 2; ++n)
#pragma unroll
        for (int kk = 0; kk < 2; ++kk)
          b1q[n][kk] = *(const bf16x8*)(sB + offB[n][kk]);
    }
    BAR();
    __builtin_amdgcn_s_setprio(1);
#pragma unroll
    for (int m = 0; m < 4; ++m)
#pragma unroll
      for (int n = 0; n < 2; ++n)
#pragma unroll
        for (int kk = 0; kk < 2; ++kk)
          acc[m][n + 2] = __builtin_amdgcn_mfma_f32_16x16x32_bf16(
              aq[m][kk], b1q[n][kk], acc[m][n + 2], 0, 0, 0);
    __builtin_amdgcn_s_setprio(0);
    BAR();

    // ---------- Phase 3: stage B0(t+2) | read aq(A1) | m4-7 x n2-3
    if (s2) STAGE(pB[0], cur, 2);
    {
      const char* sA = (const char*)&lds[cur][1][0];
#pragma unroll
      for (int m = 0; m < 4; ++m)
#pragma unroll
        for (int kk = 0; kk < 2; ++kk)
          aq[m][kk] = *(const bf16x8*)(sA + offA[m][kk]);
    }
    BAR();
    __builtin_amdgcn_s_setprio(1);
#pragma unroll
    for (int m = 0; m < 4; ++m)
#pragma unroll
      for (int n = 0; n < 2; ++n)
#pragma unroll
        for (int kk = 0; kk < 2; ++kk)
          acc[m + 4][n + 2] = __builtin_amdgcn_mfma_f32_16x16x32_bf16(
              aq[m][kk], b1q[n][kk], acc[m + 4][n + 2], 0, 0, 0);
    __builtin_amdgcn_s_setprio(0);
    BAR();

    // ---------- Phase 4: stage B1(t+2) | (no reads) | m4-7 x n0-1
    if (s2) STAGE(pB[1], cur, 3);
    BAR();
    __builtin_amdgcn_s_setprio(1);
#pragma unroll
    for (int m = 0; m < 4; ++m)
#pragma unroll
      for (int n = 0; n < 2; ++n)
#pragma unroll
        for (int kk = 0; kk < 2; ++kk)
          acc[m + 4][n] = __builtin_amdgcn_mfma_f32_16x16x32_bf16(
              aq[m][kk], b0q[n][kk], acc[m + 4][n], 0, 0, 0);
    __builtin_amdgcn_s_setprio(0);

    // ---------- tile boundary: counted wait, never drain mid-stream
    if (t < nk - 1) {
      if (s2) asm volatile("s_waitcnt vmcnt(6)" ::: "memory");
      else    asm volatile("s_waitcnt vmcnt(0)" ::: "memory");
      BAR();
    }
  }

  // ---- epilogue: C/D layout col=lane&15, row=(lane>>4)*4+reg
  const int q = lane >> 4;
  if (EPI == 0) {
    short* C = (short*)Cout;
#pragma unroll
    for (int m = 0; m < 8; ++m) {
      const int row0 = brow * 256 + wr * 128 + m * 16 + q * 4;
#pragma unroll
      for (int n = 0; n < 4; ++n) {
        const int col = bcol * 256 + wc * 64 + n * 16 + fr;
        const float bv = bias[col];
#pragma unroll
        for (int j = 0; j < 4; ++j) {
          float v = acc[m][n][j] + bv;
          v = v > 0.f ? v * v : 0.f;   // squared ReLU
          C[(size_t)(row0 + j) * N + col] = f2bf(v);
        }
      }
    }
  } else {
    float* C = (float*)Cout;
#pragma unroll
    for (int m = 0; m < 8; ++m) {
      const int row0 = brow * 256 + wr * 128 + m * 16 + q * 4;
#pragma unroll
      for (int n = 0; n < 4; ++n) {
        const int col = bcol * 256 + wc * 64 + n * 16 + fr;
        const float bv = bias[col];
#pragma unroll
        for (int j = 0; j < 4; ++j)
          C[(size_t)(row0 + j) * N + col] = acc[m][n][j] + bv;
      }
    }
  }
#undef STAGE
}

// ---- launch -------------------------------------------------------------

extern "C" void kernel_launch(void* const* d_in, const int* in_sizes, int n_in,
                              void* d_out, int out_size, void* d_ws,
                              size_t ws_size, hipStream_t stream) {
  const float* x  = (const float*)d_in[0];
  const float* w1 = (const float*)d_in[1];
  const float* b1 = (const float*)d_in[2];
  const float* w2 = (const float*)d_in[3];
  const float* b2 = (const float*)d_in[4];
  float* out = (float*)d_out;

  const int H = in_sizes[2];            // 8192
  const int D = in_sizes[4];            // 2048
  const int M = in_sizes[0] / D;        // B*S = 8192

  // workspace layout (all bf16 as short):
  short* xb  = (short*)d_ws;                 // M*D
  short* w1b = xb  + (size_t)M * D;          // H*D
  short* w2b = w1b + (size_t)H * D;          // D*H
  short* act = w2b + (size_t)D * H;          // M*H

  {
    int n4 = (M * D) / 4;
    cvt_f32_bf16<<<(n4 + 255) / 256, 256, 0, stream>>>(x, xb, n4);
    n4 = (H * D) / 4;
    cvt_f32_bf16<<<(n4 + 255) / 256, 256, 0, stream>>>(w1, w1b, n4);
    n4 = (D * H) / 4;
    cvt_f32_bf16<<<(n4 + 255) / 256, 256, 0, stream>>>(w2, w2b, n4);
  }

  // GEMM1: [M,D] @ [H,D]^T -> sqrelu -> act[M,H] (bf16)
  gemm_bt<0><<<(M / 256) * (H / 256), 512, 0, stream>>>(
      xb, w1b, b1, (void*)act, M, H, D);
  // GEMM2: [M,H] @ [D,H]^T -> + b2 -> out[M,D] (f32)
  gemm_bt<1><<<(M / 256) * (D / 256), 512, 0, stream>>>(
      act, w2b, b2, (void*)out, M, D, H);
}